// Round 8
// baseline (785.204 us; speedup 1.0000x reference)
//
#include <hip/hip_runtime.h>
#include <math.h>

#define Bn 8
#define Ln 2048
#define DIMn 768
#define DIN 1536           // D_INNER
#define DSTATE 16
#define DTRANK 48
#define XPN 80             // DT_RANK + 2*D_STATE
#define NR (Bn*Ln)         // 16384 rows
#define CH 128             // scan chunk length
#define NCH (Ln/CH)        // 16 chunks
#define NDG4 (DIN/64)      // 24 channel-quadgroups (64 ch per block)
#define TL 64              // scan staging tile (timesteps)

typedef unsigned short bf16_t;
typedef __attribute__((ext_vector_type(8))) short short8;   // 8 bf16 (4 VGPR)
typedef __attribute__((ext_vector_type(4))) float f32x4;

__device__ __forceinline__ float sigf(float v){ return 1.0f/(1.0f+__expf(-v)); }
__device__ __forceinline__ float bf2f(unsigned short u){
    return __uint_as_float(((unsigned int)u) << 16);
}
__device__ __forceinline__ unsigned short f2bf(float f){
    unsigned int x = __float_as_uint(f);
    unsigned int r = (x + 0x7FFFu + ((x >> 16) & 1u)) >> 16;
    return (unsigned short)r;
}

// async global->LDS, 16B per lane; LDS dest = uniform base + lane*16
__device__ __forceinline__ void async_ld16(const bf16_t* g, bf16_t* l) {
    __builtin_amdgcn_global_load_lds(
        (const __attribute__((address_space(1))) unsigned int*)g,
        (__attribute__((address_space(3))) unsigned int*)l,
        16, 0, 0);
}

// quad-lane DPP permute-add (VALU pipe)
template<int CTRL>
__device__ __forceinline__ float dpp_qperm(float x) {
    int v = __builtin_amdgcn_update_dpp(0, __float_as_int(x), CTRL, 0xF, 0xF, true);
    return __int_as_float(v);
}

// ---------------- weight prep ----------------
__global__ __launch_bounds__(256) void f2bf_kernel(
    const float* __restrict__ in, bf16_t* __restrict__ out, int n)
{
    int i = blockIdx.x*256 + threadIdx.x;
    if (i < n) out[i] = f2bf(in[i]);
}
// W_xp (80,1536) -> (128,1536) zero row-padded
__global__ __launch_bounds__(256) void padxp_kernel(
    const float* __restrict__ W, bf16_t* __restrict__ out)
{
    int i = blockIdx.x*256 + threadIdx.x;   // < 128*1536
    int row = i / DIN, col = i % DIN;
    out[i] = (row < XPN) ? f2bf(W[row*DIN + col]) : 0;
}
// W_dt (1536,48) -> (1536,64) zero col-padded
__global__ __launch_bounds__(256) void paddt_kernel(
    const float* __restrict__ W, bf16_t* __restrict__ out)
{
    int i = blockIdx.x*256 + threadIdx.x;   // < 1536*64
    int row = i >> 6, col = i & 63;
    out[i] = (col < DTRANK) ? f2bf(W[row*DTRANK + col]) : 0;
}

// ---------------- LayerNorm + mask -> bf16 ----------------
__global__ __launch_bounds__(256) void ln_kernel(
    const float* __restrict__ x, const int* __restrict__ mask,
    const float* __restrict__ g, const float* __restrict__ bta,
    bf16_t* __restrict__ xn)
{
    int row = blockIdx.x;
    int t = threadIdx.x;
    const float* xr = x + (size_t)row * DIMn;
    float v0 = xr[t], v1 = xr[t+256], v2 = xr[t+512];
    float s  = v0+v1+v2;
    float sq = v0*v0+v1*v1+v2*v2;
    #pragma unroll
    for (int off = 32; off; off >>= 1) {
        s  += __shfl_down(s,  off, 64);
        sq += __shfl_down(sq, off, 64);
    }
    __shared__ float ls[4], lq[4];
    int wave = t >> 6, lane = t & 63;
    if (lane == 0) { ls[wave] = s; lq[wave] = sq; }
    __syncthreads();
    s  = ls[0]+ls[1]+ls[2]+ls[3];
    sq = lq[0]+lq[1]+lq[2]+lq[3];
    float mu  = s * (1.0f/DIMn);
    float var = sq * (1.0f/DIMn) - mu*mu;
    float rstd = rsqrtf(var + 1e-5f);
    float mf = (float)mask[row];
    bf16_t* o = xn + (size_t)row * DIMn;
    o[t]     = f2bf(((v0-mu)*rstd*g[t]     + bta[t])     * mf);
    o[t+256] = f2bf(((v1-mu)*rstd*g[t+256] + bta[t+256]) * mf);
    o[t+512] = f2bf(((v2-mu)*rstd*g[t+512] + bta[t+512]) * mf);
}

// ---------------- LDS-staged bf16 MFMA GEMM: C[M,N] = A[M,K] @ W[N,K]^T ------
// 128x128 tile, BK=32, 4 waves (2x2), fragment-order LDS via global_load_lds.
// __launch_bounds__(256,4): cap regs (VGPR+AGPR) at 128/wave -> 4 blocks/CU.
// XCD swizzle: m-tile group pinned to one XCD so A-tiles stay in that L2.
// EPI: 0 = store bf16, 1 = softplus(acc+bias[n]) bf16, 2 = f32 mf*(resid+acc)
template<int EPI, typename TC>
__global__ __launch_bounds__(256, 4) void mfma_gemm(
    const bf16_t* __restrict__ A, int lda,
    const bf16_t* __restrict__ W, int ldw,
    TC* __restrict__ C, int ldc, int K, int Nb,
    const float* __restrict__ bias,
    const float* __restrict__ resid, const int* __restrict__ mask)
{
    __shared__ __align__(16) bf16_t Als[8*512];
    __shared__ __align__(16) bf16_t Bls[8*512];
    int tid  = threadIdx.x;
    int wave = tid >> 6, lane = tid & 63;

    // XCD-aware swizzle (requires gridDim.y % 8 == 0)
    int GX = gridDim.x;
    int flat = blockIdx.y*GX + blockIdx.x;
    int rest = flat >> 3;
    int gx = rest % GX;
    int gy = (rest / GX)*8 + (flat & 7);
    int mblk = gy*128, nblk = gx*128;

    int lr16 = lane & 15, kq = lane >> 4;
    int wr = wave >> 1, wc = wave & 1;
    f32x4 acc[4][4] = {};

    for (int k0 = 0; k0 < K; k0 += 32) {
        #pragma unroll
        for (int q = 0; q < 4; q++) {
            int id = wave*4 + q;
            if (id < 8) {
                const bf16_t* g = A + (size_t)(mblk + id*16 + lr16)*lda + k0 + kq*8;
                async_ld16(g, Als + id*512);
            } else {
                const bf16_t* g = W + (size_t)(nblk + (id-8)*16 + lr16)*ldw + k0 + kq*8;
                async_ld16(g, Bls + (id-8)*512);
            }
        }
        __syncthreads();
        short8 a[4], b[4];
        #pragma unroll
        for (int i = 0; i < 4; i++)
            a[i] = *(const short8*)(Als + (wr*4+i)*512 + lane*8);
        #pragma unroll
        for (int i = 0; i < 4; i++)
            b[i] = *(const short8*)(Bls + (wc*4+i)*512 + lane*8);
        #pragma unroll
        for (int mt = 0; mt < 4; mt++)
            #pragma unroll
            for (int nt = 0; nt < 4; nt++)
                acc[mt][nt] = __builtin_amdgcn_mfma_f32_16x16x32_bf16(
                    a[mt], b[nt], acc[mt][nt], 0, 0, 0);
        __syncthreads();
    }

    int m0 = mblk + wr*64, n0 = nblk + wc*64;
    int rb = kq*4;
    #pragma unroll
    for (int mt = 0; mt < 4; mt++) {
        #pragma unroll
        for (int nt = 0; nt < 4; nt++) {
            int col = n0 + nt*16 + lr16;
            if (col >= Nb) continue;
            #pragma unroll
            for (int r = 0; r < 4; r++) {
                int row = m0 + mt*16 + rb + r;
                float v = acc[mt][nt][r];
                if (EPI == 1) {
                    float u = v + bias[col];
                    v = (u > 20.f) ? u : log1pf(__expf(u));
                } else if (EPI == 2) {
                    v = (float)mask[row] * (resid[(size_t)row*ldc + col] + v);
                }
                if constexpr (sizeof(TC) == 2)
                    C[(size_t)row*ldc + col] = f2bf(v);
                else
                    C[(size_t)row*ldc + col] = v;
            }
        }
    }
}

// ---------------- depthwise causal conv (width 4) + SiLU, 8 ch/thread --------
__global__ __launch_bounds__(256) void conv_silu_kernel(
    const bf16_t* __restrict__ xz,
    const float* __restrict__ cw,
    const float* __restrict__ cb,
    bf16_t* __restrict__ xc)
{
    int idx = blockIdx.x*256 + threadIdx.x;       // over NR*DIN/8
    int dh = idx % (DIN/8);
    int r  = idx / (DIN/8);
    int l  = r & (Ln-1);
    int d  = dh*8;
    float w[8][4], a[8];
    #pragma unroll
    for (int c = 0; c < 8; c++) {
        float4 wv = *(const float4*)(cw + (size_t)(d+c)*4);
        w[c][0]=wv.x; w[c][1]=wv.y; w[c][2]=wv.z; w[c][3]=wv.w;
        a[c] = cb[d+c];
    }
    #pragma unroll
    for (int j = 0; j < 4; j++) {
        int ll = l - 3 + j;
        if (ll >= 0) {
            short8 v = *(const short8*)(xz + (size_t)(r-3+j)*(2*DIN) + d);
            #pragma unroll
            for (int c = 0; c < 8; c++)
                a[c] = fmaf(bf2f(((unsigned short*)&v)[c]), w[c][j], a[c]);
        }
    }
    short8 o;
    #pragma unroll
    for (int c = 0; c < 8; c++) {
        float s = a[c]*sigf(a[c]);
        ((unsigned short*)&o)[c] = f2bf(s);
    }
    *(short8*)(xc + (size_t)r*DIN + d) = o;
}

// =============== selective scan, 4 waves/block (64 channels), shared B/C =====
// block = (b, 64-ch group dg4, chunk ch). 256 thr: wave w (16 ch), lane l:
// c16 = l>>2 (channel in wave), g = l&3 (4 states 4g..4g+3).

// ---------------- scan pass 1: per-chunk local end-state ---------------------
__global__ __launch_bounds__(256) void scan1_kernel(
    const bf16_t* __restrict__ dtb,   // (NR, DIN)
    const bf16_t* __restrict__ xcb,   // (NR, DIN)
    const bf16_t* __restrict__ xdbl,  // (NR, 80): cols 48..63 = B
    const float* __restrict__ A_log,
    float* __restrict__ hend,         // per (bdg,ch): 256 lanes x float4
    float* __restrict__ sumdt)        // per (bdg,ch): 64 ch
{
    __shared__ bf16_t dts[TL][72];
    __shared__ bf16_t xcs[TL][72];
    __shared__ float  Bf [TL][16];

    int t = threadIdx.x;
    int w = t >> 6, l = t & 63;
    int c16 = l >> 2, g = l & 3;
    int blk = blockIdx.x;
    int ch  = blk & (NCH-1);
    int bdg = blk >> 4;                 // b*NDG4 + dg4
    int b   = bdg / NDG4, dg4 = bdg % NDG4;
    int d0  = dg4*64;
    int d   = d0 + w*16 + c16;
    int wc  = w*16 + c16;

    float4 a4 = *(const float4*)(A_log + (size_t)d*DSTATE + 4*g);
    float A2[4], h[4] = {0.f,0.f,0.f,0.f};
    A2[0] = -__expf(a4.x)*1.44269504f; A2[1] = -__expf(a4.y)*1.44269504f;
    A2[2] = -__expf(a4.z)*1.44269504f; A2[3] = -__expf(a4.w)*1.44269504f;
    float sdt = 0.f;
    size_t rbase = (size_t)b*Ln + (size_t)ch*CH;

    int tl = t >> 2, qq = t & 3;        // staging role: row tl, 16-ch slice qq
    for (int l0 = 0; l0 < CH; l0 += TL) {
        size_t row = rbase + l0 + tl;
        *(short8*)&dts[tl][qq*16]   = *(const short8*)(dtb + row*DIN + d0 + qq*16);
        *(short8*)&dts[tl][qq*16+8] = *(const short8*)(dtb + row*DIN + d0 + qq*16 + 8);
        *(short8*)&xcs[tl][qq*16]   = *(const short8*)(xcb + row*DIN + d0 + qq*16);
        *(short8*)&xcs[tl][qq*16+8] = *(const short8*)(xcb + row*DIN + d0 + qq*16 + 8);
        if (qq < 2) {   // B: 16 values via 2 threads x 8
            short8 bv = *(const short8*)(xdbl + row*XPN + DTRANK + qq*8);
            #pragma unroll
            for (int j = 0; j < 8; j++)
                Bf[tl][qq*8+j] = bf2f(((unsigned short*)&bv)[j]);
        }
        __syncthreads();
        #pragma unroll 8
        for (int ll = 0; ll < TL; ll++) {
            float dtv = bf2f(dts[ll][wc]);
            float xv  = bf2f(xcs[ll][wc]);
            sdt += dtv;
            float u = dtv * xv;
            float4 Bv = *(const float4*)&Bf[ll][4*g];
            #pragma unroll
            for (int j = 0; j < 4; j++) {
                float e = __builtin_amdgcn_exp2f(dtv * A2[j]);
                h[j] = e*h[j] + u*((const float*)&Bv)[j];
            }
        }
        __syncthreads();
    }
    size_t hbase = ((size_t)(bdg*NCH + ch)*256 + t)*4;
    *(float4*)&hend[hbase] = make_float4(h[0], h[1], h[2], h[3]);
    if (g == 0) sumdt[(size_t)(bdg*NCH + ch)*64 + wc] = sdt;
}

// ---------------- scan pass 2: prefix-fixup + local scan + y + gate ----------
__global__ __launch_bounds__(256) void scan2_kernel(
    const bf16_t* __restrict__ dtb,
    const bf16_t* __restrict__ xcb,
    const bf16_t* __restrict__ xdbl,  // cols 48..63=B, 64..79=C
    bf16_t* __restrict__ xz,          // z read at +DIN, yg write at +0
    const float* __restrict__ A_log,
    const float* __restrict__ Dp,
    const float* __restrict__ hend,
    const float* __restrict__ sumdt)
{
    __shared__ bf16_t dts[TL][72];
    __shared__ bf16_t xcs[TL][72];
    __shared__ bf16_t ybuf[TL][72];
    __shared__ float  Bf [TL][16];
    __shared__ float  Cf [TL][16];

    int t = threadIdx.x;
    int w = t >> 6, l = t & 63;
    int c16 = l >> 2, g = l & 3;
    int blk = blockIdx.x;
    int ch  = blk & (NCH-1);
    int bdg = blk >> 4;
    int b   = bdg / NDG4, dg4 = bdg % NDG4;
    int d0  = dg4*64;
    int d   = d0 + w*16 + c16;
    int wc  = w*16 + c16;

    float4 a4 = *(const float4*)(A_log + (size_t)d*DSTATE + 4*g);
    float A2[4], h[4] = {0.f,0.f,0.f,0.f};
    A2[0] = -__expf(a4.x)*1.44269504f; A2[1] = -__expf(a4.y)*1.44269504f;
    A2[2] = -__expf(a4.z)*1.44269504f; A2[3] = -__expf(a4.w)*1.44269504f;
    float Dv = Dp[d];

    // chunk-prefix from earlier chunks
    for (int cc = 0; cc < ch; cc++) {
        float sd = sumdt[(size_t)(bdg*NCH + cc)*64 + wc];
        float4 he = *(const float4*)&hend[((size_t)(bdg*NCH + cc)*256 + t)*4];
        #pragma unroll
        for (int j = 0; j < 4; j++) {
            float e = __builtin_amdgcn_exp2f(A2[j]*sd);
            h[j] = e*h[j] + ((const float*)&he)[j];
        }
    }

    size_t rbase = (size_t)b*Ln + (size_t)ch*CH;
    int tl = t >> 2, qq = t & 3;
    for (int l0 = 0; l0 < CH; l0 += TL) {
        size_t row = rbase + l0 + tl;
        *(short8*)&dts[tl][qq*16]   = *(const short8*)(dtb + row*DIN + d0 + qq*16);
        *(short8*)&dts[tl][qq*16+8] = *(const short8*)(dtb + row*DIN + d0 + qq*16 + 8);
        *(short8*)&xcs[tl][qq*16]   = *(const short8*)(xcb + row*DIN + d0 + qq*16);
        *(short8*)&xcs[tl][qq*16+8] = *(const short8*)(xcb + row*DIN + d0 + qq*16 + 8);
        {   // B|C: 32 values via 4 threads x 8
            short8 v = *(const short8*)(xdbl + row*XPN + DTRANK + qq*8);
            float* dst = (qq < 2) ? &Bf[tl][qq*8] : &Cf[tl][(qq-2)*8];
            #pragma unroll
            for (int j = 0; j < 8; j++)
                dst[j] = bf2f(((unsigned short*)&v)[j]);
        }
        __syncthreads();
        #pragma unroll 8
        for (int ll = 0; ll < TL; ll++) {
            float dtv = bf2f(dts[ll][wc]);
            float xv  = bf2f(xcs[ll][wc]);
            float u   = dtv * xv;
            float4 Bv = *(const float4*)&Bf[ll][4*g];
            float4 Cv = *(const float4*)&Cf[ll][4*g];
            float p   = 0.f;
            #pragma unroll
            for (int j = 0; j < 4; j++) {
                float e = __builtin_amdgcn_exp2f(dtv * A2[j]);
                h[j] = e*h[j] + u*((const float*)&Bv)[j];
                p = fmaf(h[j], ((const float*)&Cv)[j], p);
            }
            p += dpp_qperm<0xB1>(p);
            p += dpp_qperm<0x4E>(p);
            if (g == 0) ybuf[ll][wc] = f2bf(p + xv*Dv);
        }
        __syncthreads();
        // gate with z, write yg
        {
            short8 z0 = *(const short8*)(xz + row*(2*DIN) + DIN + d0 + qq*16);
            short8 z1 = *(const short8*)(xz + row*(2*DIN) + DIN + d0 + qq*16 + 8);
            short8 y0 = *(const short8*)&ybuf[tl][qq*16];
            short8 y1 = *(const short8*)&ybuf[tl][qq*16+8];
            short8 o0, o1;
            #pragma unroll
            for (int j = 0; j < 8; j++) {
                float zv = bf2f(((unsigned short*)&z0)[j]);
                ((unsigned short*)&o0)[j] = f2bf(bf2f(((unsigned short*)&y0)[j]) * zv * sigf(zv));
                float zw = bf2f(((unsigned short*)&z1)[j]);
                ((unsigned short*)&o1)[j] = f2bf(bf2f(((unsigned short*)&y1)[j]) * zw * sigf(zw));
            }
            *(short8*)(xz + row*(2*DIN) + d0 + qq*16)     = o0;
            *(short8*)(xz + row*(2*DIN) + d0 + qq*16 + 8) = o1;
        }
        __syncthreads();
    }
}

extern "C" void kernel_launch(void* const* d_in, const int* in_sizes, int n_in,
                              void* d_out, int out_size, void* d_ws, size_t ws_size,
                              hipStream_t stream) {
    const float* x      = (const float*)d_in[0];
    const int*   mask   = (const int*)  d_in[1];
    const float* ln_g   = (const float*)d_in[2];
    const float* ln_b   = (const float*)d_in[3];
    const float* W_in   = (const float*)d_in[4];
    const float* conv_w = (const float*)d_in[5];
    const float* conv_b = (const float*)d_in[6];
    const float* W_xp   = (const float*)d_in[7];
    const float* W_dt   = (const float*)d_in[8];
    const float* b_dt   = (const float*)d_in[9];
    const float* A_log  = (const float*)d_in[10];
    const float* Dp     = (const float*)d_in[11];
    const float* W_out  = (const float*)d_in[12];
    float* out = (float*)d_out;

    char* wsb = (char*)d_ws;
    size_t off = 0;
    bf16_t* xz    = (bf16_t*)(wsb + off); off += (size_t)NR*3072*2;      // 100.7 MB
    bf16_t* xc    = (bf16_t*)(wsb + off); off += (size_t)NR*DIN*2;       //  50.3 MB
    bf16_t* xdbl  = (bf16_t*)(wsb + off); off += (size_t)NR*XPN*2;       //   2.6 MB
    char*   xnbR  = (wsb + off);          off += (size_t)NR*DIMn*2;      //  25.2 MB
    bf16_t* Winb  = (bf16_t*)(wsb + off); off += (size_t)(2*DIN)*DIMn*2; //   4.7 MB
    bf16_t* Woutb = (bf16_t*)(wsb + off); off += (size_t)DIMn*DIN*2;     //   2.4 MB

    bf16_t* xnb   = (bf16_t*)xnbR;
    // aliases inside xnb region (live after in_proj):
    float*  hend  = (float*)xnbR;                          // 3072*1024 f = 12.6 MB
    float*  sumdt = hend + (size_t)3072*1024;              // 3072*64 f   =  0.8 MB
    bf16_t* Wxpb  = (bf16_t*)(sumdt + (size_t)3072*64);    // 128*1536    =  0.4 MB
    bf16_t* Wdtb  = Wxpb + (size_t)128*DIN;                // 1536*64     =  0.2 MB

    bf16_t* dtb = (bf16_t*)d_out;   // dt lives in d_out until final GEMM

    // 0. big-weight conversion
    f2bf_kernel<<<(2*DIN*DIMn + 255)/256, 256, 0, stream>>>(W_in,  Winb,  2*DIN*DIMn);
    f2bf_kernel<<<(DIMn*DIN  + 255)/256, 256, 0, stream>>>(W_out, Woutb, DIMn*DIN);

    // 1. LayerNorm + mask -> xnb
    ln_kernel<<<NR, 256, 0, stream>>>(x, mask, ln_g, ln_b, xnb);

    // 2. in_proj: xz = xnb @ Winb^T  (M=16384, N=3072, K=768)
    mfma_gemm<0, bf16_t><<<dim3(3072/128, NR/128), 256, 0, stream>>>(
        xnb, DIMn, Winb, DIMn, xz, 2*DIN, DIMn, 3072, nullptr, nullptr, nullptr);

    // 2b. small padded weights (into now-dead xnb region)
    padxp_kernel<<<(128*DIN + 255)/256, 256, 0, stream>>>(W_xp, Wxpb);
    paddt_kernel<<<(DIN*64  + 255)/256, 256, 0, stream>>>(W_dt, Wdtb);

    // 3. depthwise conv + SiLU -> xc
    conv_silu_kernel<<<(NR*DIN/8)/256, 256, 0, stream>>>(xz, conv_w, conv_b, xc);

    // 4. x_proj: xdbl = xc @ Wxpb^T  (N=80 padded to 128, K=1536)
    mfma_gemm<0, bf16_t><<<dim3(1, NR/128), 256, 0, stream>>>(
        xc, DIN, Wxpb, DIN, xdbl, XPN, DIN, XPN, nullptr, nullptr, nullptr);

    // 5. dt = softplus(xdbl[:, :48] @ Wdtb^T + b_dt)  (K padded 48->64)
    mfma_gemm<1, bf16_t><<<dim3(DIN/128, NR/128), 256, 0, stream>>>(
        xdbl, XPN, Wdtb, 64, dtb, DIN, 64, DIN, b_dt, nullptr, nullptr);

    // 6. scan pass 1: per-chunk (hend, sum dt)
    scan1_kernel<<<Bn*NDG4*NCH, 256, 0, stream>>>(dtb, xc, xdbl, A_log, hend, sumdt);

    // 7. scan pass 2: prefix fixup + y + gate -> yg (x_in half of xz)
    scan2_kernel<<<Bn*NDG4*NCH, 256, 0, stream>>>(dtb, xc, xdbl, xz, A_log, Dp, hend, sumdt);

    // 8. out_proj + residual: out = mf*(x + yg @ Woutb^T)  (N=768, K=1536)
    mfma_gemm<2, float><<<dim3(DIMn/128, NR/128), 256, 0, stream>>>(
        xz, 2*DIN, Woutb, DIN, out, DIMn, DIN, DIMn, nullptr, x, mask);
}